// Round 13
// baseline (285.608 us; speedup 1.0000x reference)
//
#include <hip/hip_runtime.h>

#define BB 8
#define CC 512
#define NT 1024
#define LL 10
#define DQK 64
#define BN_EPS 1e-5f

using u16 = unsigned short;
typedef __attribute__((ext_vector_type(8))) short short8;
typedef __attribute__((ext_vector_type(4))) float f32x4;

// ---------------- helpers ----------------
__device__ __forceinline__ float waveSum(float v) {
#pragma unroll
  for (int o = 32; o; o >>= 1) v += __shfl_down(v, o, 64);
  return v;
}
__device__ __forceinline__ u16 f2bf(float f) {
  unsigned u = __float_as_uint(f);
  u += 0x7FFFu + ((u >> 16) & 1u);
  return (u16)(u >> 16);
}
__device__ __forceinline__ float bf2f(u16 h) {
  return __uint_as_float(((unsigned)h) << 16);
}
// async global->LDS, 16B/lane; LDS dest must be wave-uniform base + lane*16
__device__ __forceinline__ void g2l16(const u16* g, void* l) {
  __builtin_amdgcn_global_load_lds(
      (const __attribute__((address_space(1))) unsigned int*)g,
      (__attribute__((address_space(3))) unsigned int*)l, 16, 0, 0);
}

// hidden-mean cargo block, DMA path: 2 contiguous rows (8KB) staged to LDS via
// global_load_lds, then wave-reduced. `stage` aliases the GEMM kernel's shared
// arrays (>=8KB); `part` needs 4 floats.
__device__ __forceinline__ void hidden_mean_block_lds(
    int mb, const float* __restrict__ xh, const float* __restrict__ yh,
    float* __restrict__ lm, char* stage, float* part) {
  int row0 = mb * 2;
  const int LBC = LL * BB * CC;  // 40960 rows per tensor
  const float* src = xh;
  int r0 = row0;
  if (row0 >= LBC) { src = yh; r0 = row0 - LBC; }
  const u16* g = (const u16*)(src + (size_t)r0 * NT);
  int tid = threadIdx.x;
  g2l16(g + tid * 8, stage + tid * 16);
  g2l16(g + 2048 + tid * 8, stage + 4096 + tid * 16);
  __syncthreads();  // drains vmcnt before barrier (compiler-inserted)
  int w = tid >> 6, lane = tid & 63;
  const float4* sf = (const float4*)(stage + w * 2048);
  float4 a = sf[lane];
  float4 b = sf[lane + 64];
  float s = ((a.x + a.y) + (a.z + a.w)) + ((b.x + b.y) + (b.z + b.w));
  s = waveSum(s);
  if (lane == 0) part[w] = s;
  __syncthreads();
  if (tid < 2) lm[row0 + tid] = (part[tid * 2] + part[tid * 2 + 1]) * (1.0f / NT);
}

// ---------------- pre-work kernel (converts + transpose only) ----------------
struct PreArgs {
  const float *v1W, *v2W, *rW1, *rW2;
  u16* Wdst;
  const float *qW, *kW;
  u16 *qh, *ql, *kh, *kl;
  const float *qb, *kb, *v1b, *v2b;
  float *qkb, *vb;
  const float *x, *y;
  u16 *xth, *xtl, *yth, *ytl;
};
__global__ __launch_bounds__(256) void pre_kernel(PreArgs a) {
  __shared__ float t[64][65];
  const int blk = blockIdx.x;
  if (blk < 1024) {
    int rel = blk;  // 4 segments x 256 blocks
    const float* srcs[4] = {a.v1W, a.v2W, a.rW1, a.rW2};
    const float4* s4 = (const float4*)srcs[rel >> 8];
    int r = rel & 255;
    float4 v = s4[(size_t)r * 256 + threadIdx.x];
    uint2 o;
    o.x = (unsigned)f2bf(v.x) | ((unsigned)f2bf(v.y) << 16);
    o.y = (unsigned)f2bf(v.z) | ((unsigned)f2bf(v.w) << 16);
    ((uint2*)a.Wdst)[(size_t)rel * 256 + threadIdx.x] = o;
  } else if (blk < 1088) {
    int rel = blk - 1024;  // [0,64)
    if (rel == 0) {
      int tt = threadIdx.x;
      if (tt < 64) a.qkb[tt] = a.qb[tt];
      else if (tt < 128) a.qkb[tt] = a.kb[tt - 64];
      a.vb[tt] = a.v1b[tt]; a.vb[tt + 256] = a.v1b[tt + 256];
      a.vb[tt + 512] = a.v2b[tt]; a.vb[tt + 768] = a.v2b[tt + 256];
    }
    const float* src = (rel < 32) ? a.qW : a.kW;
    u16* dh = (rel < 32) ? a.qh : a.kh;
    u16* dl = (rel < 32) ? a.ql : a.kl;
    int r = rel & 31;
    float4 v = ((const float4*)src)[(size_t)r * 256 + threadIdx.x];
    u16 h0 = f2bf(v.x), h1 = f2bf(v.y), h2 = f2bf(v.z), h3 = f2bf(v.w);
    u16 l0 = f2bf(v.x - bf2f(h0)), l1 = f2bf(v.y - bf2f(h1));
    u16 l2 = f2bf(v.z - bf2f(h2)), l3 = f2bf(v.w - bf2f(h3));
    uint2 oh, ol;
    oh.x = (unsigned)h0 | ((unsigned)h1 << 16); oh.y = (unsigned)h2 | ((unsigned)h3 << 16);
    ol.x = (unsigned)l0 | ((unsigned)l1 << 16); ol.y = (unsigned)l2 | ((unsigned)l3 << 16);
    ((uint2*)dh)[(size_t)r * 256 + threadIdx.x] = oh;
    ((uint2*)dl)[(size_t)r * 256 + threadIdx.x] = ol;
  } else {
    int rel = blk - 1088;  // [0,2048)
    int z = rel >> 7;
    const float* src = (z < 8) ? a.x : a.y;
    u16* dh = (z < 8) ? a.xth : a.yth;
    u16* dl = (z < 8) ? a.xtl : a.ytl;
    int b = z & 7;
    int n0 = (rel & 15) * 64, c0 = ((rel >> 4) & 7) * 64;
    int tc = threadIdx.x & 63, tr = threadIdx.x >> 6;
    const float* S = src + ((size_t)b * CC + c0) * NT + n0;
#pragma unroll
    for (int r = 0; r < 16; r++) {
      int c = tr + r * 4;
      t[c][tc] = S[(size_t)c * NT + tc];
    }
    __syncthreads();
    size_t base = ((size_t)b * NT + n0) * CC + c0;
#pragma unroll
    for (int r = 0; r < 16; r++) {
      int n = tr + r * 4;
      float v = t[tc][n];
      u16 h = f2bf(v);
      dh[base + (size_t)n * CC + tc] = h;
      dl[base + (size_t)n * CC + tc] = f2bf(v - bf2f(h));
    }
  }
}

// ---------------- gamma scalars ----------------
__global__ __launch_bounds__(256) void gamma_kernel(
    const float* __restrict__ lm,
    const float* __restrict__ hw1, const float* __restrict__ hw2,
    const float* __restrict__ g1W1, const float* __restrict__ g1b1,
    const float* __restrict__ g1W2, const float* __restrict__ g1b2,
    const float* __restrict__ g2W1, const float* __restrict__ g2b1,
    const float* __restrict__ g2W2, const float* __restrict__ g2b2,
    float* __restrict__ gamma) {
  int which = blockIdx.x >> 3;
  int b = blockIdx.x & 7;
  const float* hw = which ? hw2 : hw1;
  const float* W1 = which ? g2W1 : g1W1;
  const float* b1 = which ? g2b1 : g1b1;
  const float* W2 = which ? g2W2 : g1W2;
  const float* b2 = which ? g2b2 : g1b2;
  __shared__ float sxhw[CC];
  __shared__ float wsm[LL];
  if (threadIdx.x == 0) {
    float mx = -1e30f;
    for (int l = 0; l < LL; l++) mx = fmaxf(mx, hw[l]);
    float den = 0.f, e[LL];
    for (int l = 0; l < LL; l++) { e[l] = __expf(hw[l] - mx); den += e[l]; }
    for (int l = 0; l < LL; l++) wsm[l] = e[l] / den;
  }
  __syncthreads();
  const float* lmb = lm + (size_t)which * LL * BB * CC + b * CC;
  for (int c = threadIdx.x; c < CC; c += blockDim.x) {
    float a = 0.f;
    for (int l = 0; l < LL; l++) a += wsm[l] * lmb[l * BB * CC + c];
    sxhw[c] = a;
  }
  __syncthreads();
  float contrib = 0.f;
  if (threadIdx.x < 64) {
    int d = threadIdx.x;
    float a = b1[d];
    const float* wr = W1 + d * CC;
    for (int c = 0; c < CC; c++) a = fmaf(wr[c], sxhw[c], a);
    contrib = W2[d] * fmaxf(a, 0.f);
  }
  contrib = waveSum(contrib);
  if (threadIdx.x == 0) gamma[which * BB + b] = contrib + b2[0];
}

// ---------------- P [b][n][m] bf16 -> attnT[m][n] = P[n][m]/rowsum[n] ----------------
// rowsum reduced in-block from pRS partials (16 per row).
__global__ __launch_bounds__(256) void transpose_attn_kernel(
    const u16* __restrict__ attn, u16* __restrict__ attnT,
    const float* __restrict__ pRS) {
  __shared__ u16 t[64][66];
  __shared__ float rl[64];
  int b = blockIdx.z;
  int n0 = blockIdx.y * 64, m0 = blockIdx.x * 64;
  int tc = threadIdx.x & 63, tr = threadIdx.x >> 6;
  if (threadIdx.x < 64) {
    const float* pr = pRS + ((size_t)b * NT + n0 + threadIdx.x) * 16;
    float s = 0.f;
#pragma unroll
    for (int k = 0; k < 16; k++) s += pr[k];
    rl[threadIdx.x] = 1.0f / s;
  }
  const u16* S = attn + ((size_t)b * NT + n0) * NT + m0;
#pragma unroll
  for (int r = 0; r < 16; r++) {
    int nr = tr + r * 4;
    t[nr][tc] = S[(size_t)nr * NT + tc];
  }
  __syncthreads();
  u16* D = attnT + ((size_t)b * NT + m0) * NT + n0;
  float ri = rl[tc];
#pragma unroll
  for (int r = 0; r < 16; r++) {
    int mr = tr + r * 4;
    D[(size_t)mr * NT + tc] = f2bf(bf2f(t[tc][mr]) * ri);
  }
}

// ---------------- bf16 MFMA GEMM: Out[i][j] = (sum_k A[i][k]*B[j][k] + bias)*scale ----
// Flattened-grid mode (nReal>0): blocks >= nReal run hidden-mean DMA cargo (tail).
// SMODE: 0 none; 1 token-major BN-stats partials; 2 channel-major partials.
// GMODE: 0 scale=scale[bz]; 1 per-row gamma scale[(row>>13)*8+((row>>10)&7)];
//        2 per-row 1/rowsum from pRS partials (bz<8 only; scale arg = pRS).
// BMODE: 0 B via global_load_lds; 1 B reg-staged with fused BN apply+relu.
template <int BN, int SMODE, int GMODE, int BMODE>
__global__ __launch_bounds__(256) void gemm_bf16(
    const u16* __restrict__ A, long long sA, int lda,
    const u16* __restrict__ B, long long sB, long long sB2, int ldb,
    void* __restrict__ C, long long sC, int ldc,
    int K, int storef32,
    const float* __restrict__ bias_row, int brs,
    const float* __restrict__ scale,
    float* __restrict__ pS, float* __restrict__ pS2,
    const float* __restrict__ bnsc, const float* __restrict__ bnsh,
    int xbits, int ybits, int nReal,
    int meanBase, const float* __restrict__ xh, const float* __restrict__ yh,
    float* __restrict__ lm) {
  constexpr int BM = 128, BK = 32;
  constexpr int WN = (BN == 128) ? 2 : 1;
  constexpr int WM = 4 / WN;
  constexpr int FM = BM / (WM * 16);
  constexpr int FN = BN / (WN * 16);
  __shared__ u16 As[BM * BK];   // 8KB — aliased as mean-cargo stage
  __shared__ u16 Bs[BN * BK];
  __shared__ float rsv_l[BM];
  int bx, by, bz;
  if (nReal > 0) {
    int id = blockIdx.x;
    if (id >= nReal) {
      hidden_mean_block_lds(meanBase + (id - nReal), xh, yh, lm,
                            (char*)As, rsv_l);
      return;
    }
    bx = id & ((1 << xbits) - 1);
    by = (id >> xbits) & ((1 << ybits) - 1);
    bz = id >> (xbits + ybits);
  } else {
    bx = blockIdx.x; by = blockIdx.y; bz = blockIdx.z;
  }
  const int i0 = by * BM;
  const int j0 = bx * BN;
  const u16* Ab = A + (size_t)bz * sA + (size_t)i0 * lda;
  const u16* Bb = B + (size_t)(bz & 7) * sB + (size_t)(bz >> 3) * sB2 + (size_t)j0 * ldb;
  const int tid = threadIdx.x;
  const int lane = tid & 63;
  const int wave = tid >> 6;
  const int wr = wave / WN, wc = wave % WN;
  const int fr = lane & 15;
  const int kg = lane >> 4;
  const int arow = tid >> 2;
  const int aq = tid & 3;

  if constexpr (GMODE == 2) {
    if (bz < 8 && tid < BM) {
      const float* pr = scale + ((size_t)bz * NT + i0 + tid) * 16;
      float s = 0.f;
#pragma unroll
      for (int k = 0; k < 16; k++) s += pr[k];
      rsv_l[tid] = 1.0f / s;
    }
  }

  f32x4 acc[FM][FN] = {};

  for (int k0 = 0; k0 < K; k0 += BK) {
#pragma unroll
    for (int c = 0; c < (BM * BK * 2) / 4096; c++)
      g2l16(Ab + (size_t)(arow + c * 64) * lda + k0 + aq * 8,
            (char*)As + c * 4096 + tid * 16);
    if constexpr (BMODE == 0) {
#pragma unroll
      for (int c = 0; c < (BN * BK * 2) / 4096; c++)
        g2l16(Bb + (size_t)(arow + c * 64) * ldb + k0 + aq * 8,
              (char*)Bs + c * 4096 + tid * 16);
    } else {
      static_assert(BN == 64 || BMODE == 0, "BMODE=1 requires BN=64");
      short8 v = *(const short8*)(Bb + (size_t)arow * ldb + k0 + aq * 8);
      const float* scp = bnsc + (size_t)bz * 512 + k0 + aq * 8;
      const float* shp = bnsh + (size_t)bz * 512 + k0 + aq * 8;
      short8 o;
#pragma unroll
      for (int e = 0; e < 8; e++) {
        float f = fmaxf(fmaf(bf2f((u16)v[e]), scp[e], shp[e]), 0.f);
        o[e] = (short)f2bf(f);
      }
      *(short8*)((char*)Bs + tid * 16) = o;
    }
    __syncthreads();
    short8 fa[FM], fb[FN];
#pragma unroll
    for (int i = 0; i < FM; i++)
      fa[i] = *(const short8*)&As[(wr * FM * 16 + i * 16 + fr) * BK + kg * 8];
#pragma unroll
    for (int j = 0; j < FN; j++)
      fb[j] = *(const short8*)&Bs[(wc * FN * 16 + j * 16 + fr) * BK + kg * 8];
#pragma unroll
    for (int i = 0; i < FM; i++)
#pragma unroll
      for (int j = 0; j < FN; j++)
        acc[i][j] = __builtin_amdgcn_mfma_f32_16x16x32_bf16(fa[i], fb[j], acc[i][j], 0, 0, 0);
    __syncthreads();
  }

  const float scl = (GMODE == 0 && scale) ? scale[bz] : 1.0f;
  const float* brow = bias_row ? bias_row + (size_t)bz * brs : nullptr;
  float* Cf = (float*)C + (size_t)bz * sC;
  u16* Ch = (u16*)C + (size_t)bz * sC;
  float cs[FN] = {}, cs2[FN] = {};         // SMODE 1: per-col partials
  float rs[FM * 4] = {}, rs2[FM * 4] = {}; // SMODE 2: per-row partials
#pragma unroll
  for (int i = 0; i < FM; i++) {
#pragma unroll
    for (int j = 0; j < FN; j++) {
      int col = j0 + wc * FN * 16 + j * 16 + fr;
#pragma unroll
      for (int r = 0; r < 4; r++) {
        int row = i0 + wr * FM * 16 + i * 16 + kg * 4 + r;
        float rb = brow ? brow[row] : 0.0f;
        float sc2 = scl;
        if constexpr (GMODE == 1) sc2 = scale[((row >> 13) << 3) + ((row >> 10) & 7)];
        if constexpr (GMODE == 2) sc2 = (bz < 8) ? rsv_l[row - i0] : 1.0f;
        float v = (acc[i][j][r] + rb) * sc2;
        if constexpr (SMODE == 1) { cs[j] += v; cs2[j] += v * v; }
        if constexpr (SMODE == 2) { rs[i * 4 + r] += v; rs2[i * 4 + r] += v * v; }
        if (storef32) Cf[(size_t)row * ldc + col] = v;
        else Ch[(size_t)row * ldc + col] = f2bf(v);
      }
    }
  }

  if constexpr (SMODE == 1) {
    __shared__ float sred[2][4][FN][16];
#pragma unroll
    for (int j = 0; j < FN; j++) {
      float s = cs[j], s2 = cs2[j];
      s += __shfl_xor(s, 16, 64); s += __shfl_xor(s, 32, 64);
      s2 += __shfl_xor(s2, 16, 64); s2 += __shfl_xor(s2, 32, 64);
      if (lane < 16) { sred[0][wr][j][lane] = s; sred[1][wr][j][lane] = s2; }
    }
    __syncthreads();
    if (tid < FN * 16) {
      int j = tid >> 4, f = tid & 15;
      float s = sred[0][0][j][f] + sred[0][1][j][f] + sred[0][2][j][f] + sred[0][3][j][f];
      float s2 = sred[1][0][j][f] + sred[1][1][j][f] + sred[1][2][j][f] + sred[1][3][j][f];
      int col = j0 + j * 16 + f;
      int chain = by >> 6, ib = by & 63;
      pS[((size_t)chain * 512 + col) * 64 + ib] = s;
      pS2[((size_t)chain * 512 + col) * 64 + ib] = s2;
    }
  }
  if constexpr (SMODE == 2) {
#pragma unroll
    for (int i = 0; i < FM; i++)
#pragma unroll
      for (int r = 0; r < 4; r++) {
        float s = rs[i * 4 + r], s2 = rs2[i * 4 + r];
        s += __shfl_xor(s, 1, 64); s += __shfl_xor(s, 2, 64);
        s += __shfl_xor(s, 4, 64); s += __shfl_xor(s, 8, 64);
        s2 += __shfl_xor(s2, 1, 64); s2 += __shfl_xor(s2, 2, 64);
        s2 += __shfl_xor(s2, 4, 64); s2 += __shfl_xor(s2, 8, 64);
        if (fr == 0) {
          int row = i0 + wr * FM * 16 + i * 16 + kg * 4 + r;
          pS[((size_t)bz * 512 + row) * 128 + bx] = s;
          pS2[((size_t)bz * 512 + row) * 128 + bx] = s2;
        }
      }
  }
}

// ---------------- split-bf16 GEMM (~fp32 accuracy): Out = A*B^T, A,B = hi+lo ----------------
// EMODE 0: store split bf16 pair (Ch,Cl). EMODE 1: P=exp(out-20)->bf16 + rowsum partials.
// Appended hidden-mean DMA cargo (blocks >= nReal).
template <int EMODE>
__global__ __launch_bounds__(256) void gemm_split(
    const u16* __restrict__ Ah_, const u16* __restrict__ Al_, long long sA, int lda,
    const u16* __restrict__ Bh_, const u16* __restrict__ Bl_, long long sB, int ldb,
    float* __restrict__ Cf, u16* __restrict__ Ch, u16* __restrict__ Cl,
    long long sC, int ldc, int K, const float* __restrict__ bias_col, int bcs,
    float* __restrict__ pRS,
    int xbits, int ybits, int nReal,
    int meanBase, const float* __restrict__ xh, const float* __restrict__ yh,
    float* __restrict__ lm) {
  constexpr int BM = 128, BN = 64, BK = 32;
  constexpr int FM = 2, FN = 4;
  __shared__ u16 Ahs[BM * BK];  // 8KB — aliased as mean-cargo stage
  __shared__ u16 Als[BM * BK];
  __shared__ u16 Bhs[BN * BK];
  __shared__ u16 Bls[BN * BK];
  int bx, by, bz;
  {
    int id = blockIdx.x;
    if (id >= nReal) {
      hidden_mean_block_lds(meanBase + (id - nReal), xh, yh, lm,
                            (char*)Ahs, (float*)Bhs);
      return;
    }
    bx = id & ((1 << xbits) - 1);
    by = (id >> xbits) & ((1 << ybits) - 1);
    bz = id >> (xbits + ybits);
  }
  const int i0 = by * BM;
  const int j0 = bx * BN;
  const u16* Abh = Ah_ + (size_t)bz * sA + (size_t)i0 * lda;
  const u16* Abl = Al_ + (size_t)bz * sA + (size_t)i0 * lda;
  const u16* Bbh = Bh_ + (size_t)bz * sB + (size_t)j0 * ldb;
  const u16* Bbl = Bl_ + (size_t)bz * sB + (size_t)j0 * ldb;
  const int tid = threadIdx.x;
  const int lane = tid & 63;
  const int wr = tid >> 6;
  const int fr = lane & 15;
  const int kg = lane >> 4;
  const int arow = tid >> 2;
  const int aq = tid & 3;

  f32x4 acc[FM][FN] = {};

  for (int k0 = 0; k0 < K; k0 += BK) {
#pragma unroll
    for (int c = 0; c < 2; c++) {
      g2l16(Abh + (size_t)(arow + c * 64) * lda + k0 + aq * 8,
            (char*)Ahs + c * 4096 + tid * 16);
      g2l16(Abl + (size_t)(arow + c * 64) * lda + k0 + aq * 8,
            (char*)Als + c * 4096 + tid * 16);
    }
    g2l16(Bbh + (size_t)arow * ldb + k0 + aq * 8, (char*)Bhs + tid * 16);
    g2l16(Bbl + (size_t)arow * ldb + k0 + aq * 8, (char*)Bls + tid * 16);
    __syncthreads();
    short8 fah[FM], fal[FM], fbh[FN], fbl[FN];
#pragma unroll
    for (int i = 0; i < FM; i++) {
      fah[i] = *(const short8*)&Ahs[(wr * 32 + i * 16 + fr) * BK + kg * 8];
      fal[i] = *(const short8*)&Als[(wr * 32 + i * 16 + fr) * BK + kg * 8];
    }
#pragma unroll
    for (int j = 0; j < FN; j++) {
      fbh[j] = *(const short8*)&Bhs[(j * 16 + fr) * BK + kg * 8];
      fbl[j] = *(const short8*)&Bls[(j * 16 + fr) * BK + kg * 8];
    }
#pragma unroll
    for (int i = 0; i < FM; i++)
#pragma unroll
      for (int j = 0; j < FN; j++) {
        acc[i][j] = __builtin_amdgcn_mfma_f32_16x16x32_bf16(fah[i], fbh[j], acc[i][j], 0, 0, 0);
        acc[i][j] = __builtin_amdgcn_mfma_f32_16x16x32_bf16(fah[i], fbl[j], acc[i][j], 0, 0, 0);
        acc[i][j] = __builtin_amdgcn_mfma_f32_16x16x32_bf16(fal[i], fbh[j], acc[i][j], 0, 0, 0);
      }
    __syncthreads();
  }

  if constexpr (EMODE == 1) {
    u16* Chb = Ch + (size_t)bz * sC;
    float rsum[FM * 4] = {};
#pragma unroll
    for (int i = 0; i < FM; i++) {
#pragma unroll
      for (int j = 0; j < FN; j++) {
        int col = j0 + j * 16 + fr;
#pragma unroll
        for (int r = 0; r < 4; r++) {
          int row = i0 + wr * 32 + i * 16 + kg * 4 + r;
          float p = __expf(acc[i][j][r] - 20.0f);
          u16 h = f2bf(p);
          Chb[(size_t)row * ldc + col] = h;
          rsum[i * 4 + r] += bf2f(h);
        }
      }
    }
#pragma unroll
    for (int i = 0; i < FM; i++)
#pragma unroll
      for (int r = 0; r < 4; r++) {
        float s = rsum[i * 4 + r];
        s += __shfl_xor(s, 1, 64); s += __shfl_xor(s, 2, 64);
        s += __shfl_xor(s, 4, 64); s += __shfl_xor(s, 8, 64);
        if (fr == 0) {
          int row = i0 + wr * 32 + i * 16 + kg * 4 + r;
          pRS[((size_t)bz * NT + row) * 16 + bx] = s;
        }
      }
  } else {
    const float* bcol = bias_col ? bias_col + (size_t)bz * bcs : nullptr;
    float* Cfb = Cf ? Cf + (size_t)bz * sC : nullptr;
    u16* Chb = Ch ? Ch + (size_t)bz * sC : nullptr;
    u16* Clb = Cl ? Cl + (size_t)bz * sC : nullptr;
#pragma unroll
    for (int i = 0; i < FM; i++) {
#pragma unroll
      for (int j = 0; j < FN; j++) {
        int col = j0 + j * 16 + fr;
        float cb = bcol ? bcol[col] : 0.0f;
#pragma unroll
        for (int r = 0; r < 4; r++) {
          int row = i0 + wr * 32 + i * 16 + kg * 4 + r;
          float v = acc[i][j][r] + cb;
          if (Cfb) {
            Cfb[(size_t)row * ldc + col] = v;
          } else {
            u16 h = f2bf(v);
            Chb[(size_t)row * ldc + col] = h;
            Clb[(size_t)row * ldc + col] = f2bf(v - bf2f(h));
          }
        }
      }
    }
  }
}

// ---------------- BN stats reduce: NP partials -> scale/shift ----------------
template <int NP>
__global__ __launch_bounds__(128) void bnstats_reduce_np(
    const float* __restrict__ pS, const float* __restrict__ pS2,
    const float* __restrict__ g, const float* __restrict__ bet,
    float* __restrict__ scale, float* __restrict__ shift) {
  int cg = blockIdx.x;  // [chain][c]
  int c = cg & 511;
  int t = threadIdx.x;
  float s = 0.f, s2 = 0.f;
  if (t < NP) { s = pS[(size_t)cg * NP + t]; s2 = pS2[(size_t)cg * NP + t]; }
  s = waveSum(s); s2 = waveSum(s2);
  __shared__ float sb[4];
  int lane = t & 63, wid = t >> 6;
  if (lane == 0) { sb[wid] = s; sb[wid + 2] = s2; }
  __syncthreads();
  if (t == 0) {
    float S = sb[0] + sb[1];
    float S2 = sb[2] + sb[3];
    const float invn = 1.0f / (BB * NT);
    float mean = S * invn;
    float var = S2 * invn - mean * mean;
    float inv = rsqrtf(var + BN_EPS);
    float sc = g[c] * inv;
    scale[cg] = sc;
    shift[cg] = bet[c] - mean * sc;
  }
}

// ---------------- BN final: z2 [2][512][8192] + x/y fp32 -> out ----------------
// Stats reduced in-block from channel-major partials (NP=128, one channel per block).
__global__ __launch_bounds__(256) void bn_final_kernel(
    const u16* __restrict__ Z2, const float* __restrict__ X, const float* __restrict__ Y,
    const float* __restrict__ pS, const float* __restrict__ pS2,
    const float* __restrict__ g, const float* __restrict__ bet,
    float* __restrict__ Out) {
  size_t e0 = (size_t)blockIdx.x * 256;
  int chain = (int)(e0 >> 20);
  int c = (int)((e0 & 1048575) >> 11);
  int cg = chain * 512 + c;
  int t = threadIdx.x;
  float s = 0.f, s2 = 0.f;
  if (t < 128) { s = pS[(size_t)cg * 128 + t]; s2 = pS2[(size_t)cg * 128 + t]; }
  s = waveSum(s); s2 = waveSum(s2);
  __shared__ float sb[8];
  int lane = t & 63, wid = t >> 6;
  if (lane == 0) { sb[wid] = s; sb[wid + 4] = s2; }
  __syncthreads();
  __shared__ float ssc, ssh;
  if (t == 0) {
    float S = sb[0] + sb[1] + sb[2] + sb[3];
    float S2 = sb[4] + sb[5] + sb[6] + sb[7];
    const float invn = 1.0f / (BB * NT);
    float mean = S * invn;
    float var = S2 * invn - mean * mean;
    float inv = rsqrtf(var + BN_EPS);
    float sc = g[c] * inv;
    ssc = sc;
    ssh = bet[c] - mean * sc;
  }
  __syncthreads();
  size_t e = e0 + t;
  size_t ec = e & 1048575;
  int r = (int)(ec & 2047);
  int b = r >> 8;
  uint2 u = ((const uint2*)Z2)[e];
  float a0 = bf2f((u16)u.x), a1 = bf2f((u16)(u.x >> 16));
  float a2 = bf2f((u16)u.y), a3 = bf2f((u16)(u.y >> 16));
  float sc = ssc, sh = ssh;
  size_t xi = ((size_t)b * CC + c) * 256 + (r & 255);
  const float* Xs = chain ? Y : X;
  float4 xv = ((const float4*)Xs)[xi];
  float4 o;
  o.x = fmaxf(fmaf(a0, sc, sh) + xv.x, 0.f);
  o.y = fmaxf(fmaf(a1, sc, sh) + xv.y, 0.f);
  o.z = fmaxf(fmaf(a2, sc, sh) + xv.z, 0.f);
  o.w = fmaxf(fmaf(a3, sc, sh) + xv.w, 0.f);
  ((float4*)(Out + (size_t)chain * 4194304))[xi] = o;
}

extern "C" void kernel_launch(void* const* d_in, const int* in_sizes, int n_in,
                              void* d_out, int out_size, void* d_ws, size_t ws_size,
                              hipStream_t stream) {
  (void)in_sizes; (void)n_in; (void)out_size; (void)ws_size;
  const float* x    = (const float*)d_in[0];
  const float* y    = (const float*)d_in[1];
  const float* xh   = (const float*)d_in[2];
  const float* yh   = (const float*)d_in[3];
  const float* qW   = (const float*)d_in[4];
  const float* qb   = (const float*)d_in[5];
  const float* kW   = (const float*)d_in[6];
  const float* kb   = (const float*)d_in[7];
  const float* v1W  = (const float*)d_in[8];
  const float* v1b  = (const float*)d_in[9];
  const float* v2W  = (const float*)d_in[10];
  const float* v2b  = (const float*)d_in[11];
  const float* hw1  = (const float*)d_in[12];
  const float* hw2  = (const float*)d_in[13];
  const float* g1W1 = (const float*)d_in[14];
  const float* g1b1 = (const float*)d_in[15];
  const float* g1W2 = (const float*)d_in[16];
  const float* g1b2 = (const float*)d_in[17];
  const float* g2W1 = (const float*)d_in[18];
  const float* g2b1 = (const float*)d_in[19];
  const float* g2W2 = (const float*)d_in[20];
  const float* g2b2 = (const float*)d_in[21];
  const float* rW1  = (const float*)d_in[22];
  // d_in[23] = rb1 dropped (BN absorbs constant bias)
  const float* bn1g = (const float*)d_in[24];
  const float* bn1b = (const float*)d_in[25];
  const float* rW2  = (const float*)d_in[26];
  // d_in[27] = rb2 dropped
  const float* bn2g = (const float*)d_in[28];
  const float* bn2b = (const float*)d_in[29];
  float* out = (float*)d_out;

  // ---- workspace layout ----
  float* ws  = (float*)d_ws;
  float* lm  = ws;                  // 81,920
  float* gam = ws + 81920;          // 16
  float* scA = ws + 81936;          // 1,024 (2 chains)
  float* shA = ws + 82960;          // 1,024
  float* qkb = ws + 83984;          // 128
  float* vb  = ws + 84112;          // 1,024
  float* pS  = ws + 85136;          // 262,144 (max 2*512*128)
  float* pS2 = ws + 347280;         // 262,144
  float* pRS = ws + 609424;         // 131,072 rowsum partials (8192x16)
  u16* U     = (u16*)(ws + 8998032);
  u16* Wqh = U;                     // 32,768 | order: Wqh,Wql,Wkh,Wkl
  u16* Wql = U + 32768;
  u16* Wkh = U + 65536;
  u16* Wkl = U + 98304;
  u16* Wv1 = U + 131072;            // 262,144 each, Wv1->Wv2 contiguous
  u16* Wv2 = U + 393216;
  u16* Wr1 = U + 655360;
  u16* Wr2 = U + 917504;
  u16* xth = U + 1179648;           // 4,194,304 each; xth->yth contiguous
  u16* yth = xth + 4194304;
  u16* xtl = yth + 4194304;
  u16* ytl = xtl + 4194304;
  u16* q_h = ytl + 4194304;         // 524,288 each; q->k stride 1,048,576
  u16* q_l = q_h + 524288;
  u16* k_h = q_l + 524288;
  u16* k_l = k_h + 524288;
  u16* v1  = k_l + 524288;          // 4,194,304 each; v1->v2 contiguous
  u16* v2  = v1 + 4194304;
  u16* attn  = v2 + 4194304;        // 8,388,608 (unnormalized P)
  u16* attnT = attn + 8388608;      // 8,388,608 (normalized, contiguous after attn)
  // overlays (stream-serialized lifetimes):
  u16* o1t = xth;   // [2][8192][512] token-major outs (pre-gamma)
  u16* z0  = v1;    // [2][8192][512] conv1 out (M=16384 merged, gamma applied)
  u16* z2  = attn;  // [2][512][8192] conv2 out (cm)

  // 1) pre-work: weight converts + x/y transpose (hidden means ride in GEMMs below)
  PreArgs pa;
  pa.v1W = v1W; pa.v2W = v2W; pa.rW1 = rW1; pa.rW2 = rW2; pa.Wdst = Wv1;
  pa.qW = qW; pa.kW = kW; pa.qh = Wqh; pa.ql = Wql; pa.kh = Wkh; pa.kl = Wkl;
  pa.qb = qb; pa.kb = kb; pa.v1b = v1b; pa.v2b = v2b; pa.qkb = qkb; pa.vb = vb;
  pa.x = x; pa.y = y; pa.xth = xth; pa.xtl = xtl; pa.yth = yth; pa.ytl = ytl;
  pre_kernel<<<3136, 256, 0, stream>>>(pa);

  // 2) v-projections (BN=128, 512 real) + 10240 DMA mean blocks (2 rows each)
  gemm_bf16<128, 0, 0, 0><<<512 + 10240, 256, 0, stream>>>(
      Wv1, 262144, CC, xth, 4194304, 0, CC, v1, 4194304, BB * NT, CC, 0, vb, 512,
      nullptr, nullptr, nullptr, nullptr, nullptr, 6, 2, 512, 0, xh, yh, lm);
  // q/k projections (128 real) + 6144 mean blocks
  gemm_split<0><<<128 + 6144, 256, 0, stream>>>(
      xth, xtl, 4194304, CC, Wqh, Wql, 65536, CC,
      nullptr, q_h, q_l, 1048576, DQK, CC, qkb, 64, nullptr,
      0, 6, 128, 10240, xh, yh, lm);

  // 3) scores -> P = exp(S-20) bf16 + rowsum partials (1024 real) + 8192 mean blocks
  gemm_split<1><<<1024 + 8192, 256, 0, stream>>>(
      q_h, q_l, (long long)NT * DQK, DQK, k_h, k_l, (long long)NT * DQK, DQK,
      nullptr, attn, nullptr, (long long)NT * NT, NT, DQK, nullptr, 0, pRS,
      4, 3, 1024, 16384, xh, yh, lm);
  transpose_attn_kernel<<<dim3(16, 16, 8), 256, 0, stream>>>(attn, attnT, pRS);

  // 4) attention-apply (BN=128, 512 real; out1 row-normalized from pRS) + 16384 mean
  gemm_bf16<128, 0, 2, 0><<<512 + 16384, 256, 0, stream>>>(
      attn, (long long)NT * NT, NT, v1, NT, 4194304, BB * NT,
      o1t, (long long)NT * CC, CC, NT, 0, nullptr, 0, pRS, nullptr, nullptr,
      nullptr, nullptr, 2, 3, 512, 24576, xh, yh, lm);

  // 5) gamma (lm complete), then residual chains
  gamma_kernel<<<16, 256, 0, stream>>>(lm, hw1, hw2, g1W1, g1b1, g1W2, g1b2,
                                       g2W1, g2b1, g2W2, g2b2, gam);
  // conv1: per-row gamma + fused token-major stats (M=16384 merged)
  gemm_bf16<64, 1, 1, 0><<<dim3(8, 128, 1), 256, 0, stream>>>(
      o1t, 0, CC, Wr1, 0, 0, CC, z0, 0, CC, CC, 0, nullptr, 0, gam, pS, pS2,
      nullptr, nullptr, 0, 0, 0, 0, nullptr, nullptr, nullptr);
  bnstats_reduce_np<64><<<1024, 128, 0, stream>>>(pS, pS2, bn1g, bn1b, scA, shA);
  // conv2: B = bn_apply(z0) fused into reg-staging; channel-major stats fused
  gemm_bf16<64, 2, 0, 1><<<dim3(128, 4, 2), 256, 0, stream>>>(
      Wr2, 0, CC, z0, 4194304, 0, CC, z2, 4194304, BB * NT, CC, 0, nullptr, 0, nullptr,
      pS, pS2, scA, shA, 0, 0, 0, 0, nullptr, nullptr, nullptr);
  // bn_final: stats reduced in-block from NP=128 partials
  bn_final_kernel<<<8192, 256, 0, stream>>>(z2, x, y, pS, pS2, bn2g, bn2b, out);
}

// Round 14
// 258.986 us; speedup vs baseline: 1.1028x; 1.1028x over previous
//
#include <hip/hip_runtime.h>

#define BB 8
#define CC 512
#define NT 1024
#define LL 10
#define DQK 64
#define BN_EPS 1e-5f

using u16 = unsigned short;
typedef __attribute__((ext_vector_type(8))) short short8;
typedef __attribute__((ext_vector_type(4))) float f32x4;
typedef __attribute__((ext_vector_type(4))) float nf4;  // native vec for nontemporal builtins

// ---------------- helpers ----------------
__device__ __forceinline__ float waveSum(float v) {
#pragma unroll
  for (int o = 32; o; o >>= 1) v += __shfl_down(v, o, 64);
  return v;
}
__device__ __forceinline__ u16 f2bf(float f) {
  unsigned u = __float_as_uint(f);
  u += 0x7FFFu + ((u >> 16) & 1u);
  return (u16)(u >> 16);
}
__device__ __forceinline__ float bf2f(u16 h) {
  return __uint_as_float(((unsigned)h) << 16);
}
// async global->LDS, 16B/lane; LDS dest must be wave-uniform base + lane*16
__device__ __forceinline__ void g2l16(const u16* g, void* l) {
  __builtin_amdgcn_global_load_lds(
      (const __attribute__((address_space(1))) unsigned int*)g,
      (__attribute__((address_space(3))) unsigned int*)l, 16, 0, 0);
}

// hidden-mean cargo block: 4 rows (wave-per-row), nontemporal loads, no LDS
__device__ __forceinline__ void hidden_mean_block(
    int mb, const float* __restrict__ xh, const float* __restrict__ yh,
    float* __restrict__ lm) {
  int wid = mb * 4 + ((int)threadIdx.x >> 6);
  int lane = threadIdx.x & 63;
  const int LBC = LL * BB * CC;  // 40960 rows per tensor
  const float* src = xh;
  int r = wid;
  if (wid >= LBC) { src = yh; r = wid - LBC; }
  const nf4* p = (const nf4*)(src + (size_t)r * NT);
  nf4 v0 = __builtin_nontemporal_load(p + lane);
  nf4 v1 = __builtin_nontemporal_load(p + 64 + lane);
  nf4 v2 = __builtin_nontemporal_load(p + 128 + lane);
  nf4 v3 = __builtin_nontemporal_load(p + 192 + lane);
  float s = ((v0.x + v0.y) + (v0.z + v0.w)) + ((v1.x + v1.y) + (v1.z + v1.w)) +
            ((v2.x + v2.y) + (v2.z + v2.w)) + ((v3.x + v3.y) + (v3.z + v3.w));
  s = waveSum(s);
  if (lane == 0) lm[wid] = s * (1.0f / NT);
}

// ---------------- pre-work kernel (converts + transpose only) ----------------
struct PreArgs {
  const float *v1W, *v2W, *rW1, *rW2;
  u16* Wdst;
  const float *qW, *kW;
  u16 *qh, *ql, *kh, *kl;
  const float *qb, *kb, *v1b, *v2b;
  float *qkb, *vb;
  const float *x, *y;
  u16 *xth, *xtl, *yth, *ytl;
};
__global__ __launch_bounds__(256) void pre_kernel(PreArgs a) {
  __shared__ float t[64][65];
  const int blk = blockIdx.x;
  if (blk < 1024) {
    int rel = blk;  // 4 segments x 256 blocks
    const float* srcs[4] = {a.v1W, a.v2W, a.rW1, a.rW2};
    const float4* s4 = (const float4*)srcs[rel >> 8];
    int r = rel & 255;
    float4 v = s4[(size_t)r * 256 + threadIdx.x];
    uint2 o;
    o.x = (unsigned)f2bf(v.x) | ((unsigned)f2bf(v.y) << 16);
    o.y = (unsigned)f2bf(v.z) | ((unsigned)f2bf(v.w) << 16);
    ((uint2*)a.Wdst)[(size_t)rel * 256 + threadIdx.x] = o;
  } else if (blk < 1088) {
    int rel = blk - 1024;  // [0,64)
    if (rel == 0) {
      int tt = threadIdx.x;
      if (tt < 64) a.qkb[tt] = a.qb[tt];
      else if (tt < 128) a.qkb[tt] = a.kb[tt - 64];
      a.vb[tt] = a.v1b[tt]; a.vb[tt + 256] = a.v1b[tt + 256];
      a.vb[tt + 512] = a.v2b[tt]; a.vb[tt + 768] = a.v2b[tt + 256];
    }
    const float* src = (rel < 32) ? a.qW : a.kW;
    u16* dh = (rel < 32) ? a.qh : a.kh;
    u16* dl = (rel < 32) ? a.ql : a.kl;
    int r = rel & 31;
    float4 v = ((const float4*)src)[(size_t)r * 256 + threadIdx.x];
    u16 h0 = f2bf(v.x), h1 = f2bf(v.y), h2 = f2bf(v.z), h3 = f2bf(v.w);
    u16 l0 = f2bf(v.x - bf2f(h0)), l1 = f2bf(v.y - bf2f(h1));
    u16 l2 = f2bf(v.z - bf2f(h2)), l3 = f2bf(v.w - bf2f(h3));
    uint2 oh, ol;
    oh.x = (unsigned)h0 | ((unsigned)h1 << 16); oh.y = (unsigned)h2 | ((unsigned)h3 << 16);
    ol.x = (unsigned)l0 | ((unsigned)l1 << 16); ol.y = (unsigned)l2 | ((unsigned)l3 << 16);
    ((uint2*)dh)[(size_t)r * 256 + threadIdx.x] = oh;
    ((uint2*)dl)[(size_t)r * 256 + threadIdx.x] = ol;
  } else {
    int rel = blk - 1088;  // [0,2048)
    int z = rel >> 7;
    const float* src = (z < 8) ? a.x : a.y;
    u16* dh = (z < 8) ? a.xth : a.yth;
    u16* dl = (z < 8) ? a.xtl : a.ytl;
    int b = z & 7;
    int n0 = (rel & 15) * 64, c0 = ((rel >> 4) & 7) * 64;
    int tc = threadIdx.x & 63, tr = threadIdx.x >> 6;
    const float* S = src + ((size_t)b * CC + c0) * NT + n0;
#pragma unroll
    for (int r = 0; r < 16; r++) {
      int c = tr + r * 4;
      t[c][tc] = S[(size_t)c * NT + tc];
    }
    __syncthreads();
    size_t base = ((size_t)b * NT + n0) * CC + c0;
#pragma unroll
    for (int r = 0; r < 16; r++) {
      int n = tr + r * 4;
      float v = t[tc][n];
      u16 h = f2bf(v);
      dh[base + (size_t)n * CC + tc] = h;
      dl[base + (size_t)n * CC + tc] = f2bf(v - bf2f(h));
    }
  }
}

// ---------------- gamma scalars ----------------
__global__ __launch_bounds__(256) void gamma_kernel(
    const float* __restrict__ lm,
    const float* __restrict__ hw1, const float* __restrict__ hw2,
    const float* __restrict__ g1W1, const float* __restrict__ g1b1,
    const float* __restrict__ g1W2, const float* __restrict__ g1b2,
    const float* __restrict__ g2W1, const float* __restrict__ g2b1,
    const float* __restrict__ g2W2, const float* __restrict__ g2b2,
    float* __restrict__ gamma) {
  int which = blockIdx.x >> 3;
  int b = blockIdx.x & 7;
  const float* hw = which ? hw2 : hw1;
  const float* W1 = which ? g2W1 : g1W1;
  const float* b1 = which ? g2b1 : g1b1;
  const float* W2 = which ? g2W2 : g1W2;
  const float* b2 = which ? g2b2 : g1b2;
  __shared__ float sxhw[CC];
  __shared__ float wsm[LL];
  if (threadIdx.x == 0) {
    float mx = -1e30f;
    for (int l = 0; l < LL; l++) mx = fmaxf(mx, hw[l]);
    float den = 0.f, e[LL];
    for (int l = 0; l < LL; l++) { e[l] = __expf(hw[l] - mx); den += e[l]; }
    for (int l = 0; l < LL; l++) wsm[l] = e[l] / den;
  }
  __syncthreads();
  const float* lmb = lm + (size_t)which * LL * BB * CC + b * CC;
  for (int c = threadIdx.x; c < CC; c += blockDim.x) {
    float a = 0.f;
    for (int l = 0; l < LL; l++) a += wsm[l] * lmb[l * BB * CC + c];
    sxhw[c] = a;
  }
  __syncthreads();
  float contrib = 0.f;
  if (threadIdx.x < 64) {
    int d = threadIdx.x;
    float a = b1[d];
    const float* wr = W1 + d * CC;
    for (int c = 0; c < CC; c++) a = fmaf(wr[c], sxhw[c], a);
    contrib = W2[d] * fmaxf(a, 0.f);
  }
  contrib = waveSum(contrib);
  if (threadIdx.x == 0) gamma[which * BB + b] = contrib + b2[0];
}

// ---------------- P [b][n][m] bf16 -> attnT[m][n] = P[n][m]/rowsum[n] ----------------
// rowsum reduced in-block from pRS partials (16 per row).
__global__ __launch_bounds__(256) void transpose_attn_kernel(
    const u16* __restrict__ attn, u16* __restrict__ attnT,
    const float* __restrict__ pRS) {
  __shared__ u16 t[64][66];
  __shared__ float rl[64];
  int b = blockIdx.z;
  int n0 = blockIdx.y * 64, m0 = blockIdx.x * 64;
  int tc = threadIdx.x & 63, tr = threadIdx.x >> 6;
  if (threadIdx.x < 64) {
    const float* pr = pRS + ((size_t)b * NT + n0 + threadIdx.x) * 16;
    float s = 0.f;
#pragma unroll
    for (int k = 0; k < 16; k++) s += pr[k];
    rl[threadIdx.x] = 1.0f / s;
  }
  const u16* S = attn + ((size_t)b * NT + n0) * NT + m0;
#pragma unroll
  for (int r = 0; r < 16; r++) {
    int nr = tr + r * 4;
    t[nr][tc] = S[(size_t)nr * NT + tc];
  }
  __syncthreads();
  u16* D = attnT + ((size_t)b * NT + m0) * NT + n0;
  float ri = rl[tc];
#pragma unroll
  for (int r = 0; r < 16; r++) {
    int mr = tr + r * 4;
    D[(size_t)mr * NT + tc] = f2bf(bf2f(t[tc][mr]) * ri);
  }
}

// ---------------- bf16 MFMA GEMM: Out[i][j] = (sum_k A[i][k]*B[j][k] + bias)*scale ----
// Flattened-grid mode (nReal>0): blocks >= nReal run hidden-mean cargo (appended tail).
// SMODE: 0 none; 1 token-major BN-stats partials; 2 channel-major partials.
// GMODE: 0 scale=scale[bz]; 1 per-row gamma scale[(row>>13)*8+((row>>10)&7)];
//        2 per-row 1/rowsum from pRS partials (bz<8 only; scale arg = pRS).
// BMODE: 0 B via global_load_lds; 1 B reg-staged with fused BN apply+relu
//        (scale/shift from bnsc/bnsh, channel = k index, chain = bz).
template <int BN, int SMODE, int GMODE, int BMODE>
__global__ __launch_bounds__(256) void gemm_bf16(
    const u16* __restrict__ A, long long sA, int lda,
    const u16* __restrict__ B, long long sB, long long sB2, int ldb,
    void* __restrict__ C, long long sC, int ldc,
    int K, int storef32,
    const float* __restrict__ bias_row, int brs,
    const float* __restrict__ scale,
    float* __restrict__ pS, float* __restrict__ pS2,
    const float* __restrict__ bnsc, const float* __restrict__ bnsh,
    int xbits, int ybits, int nReal,
    int meanBase, const float* __restrict__ xh, const float* __restrict__ yh,
    float* __restrict__ lm) {
  constexpr int BM = 128, BK = 32;
  constexpr int WN = (BN == 128) ? 2 : 1;
  constexpr int WM = 4 / WN;
  constexpr int FM = BM / (WM * 16);
  constexpr int FN = BN / (WN * 16);
  __shared__ u16 As[BM * BK];
  __shared__ u16 Bs[BN * BK];
  __shared__ float rsv_l[BM];
  int bx, by, bz;
  if (nReal > 0) {
    int id = blockIdx.x;
    if (id >= nReal) { hidden_mean_block(meanBase + (id - nReal), xh, yh, lm); return; }
    bx = id & ((1 << xbits) - 1);
    by = (id >> xbits) & ((1 << ybits) - 1);
    bz = id >> (xbits + ybits);
  } else {
    bx = blockIdx.x; by = blockIdx.y; bz = blockIdx.z;
  }
  const int i0 = by * BM;
  const int j0 = bx * BN;
  const u16* Ab = A + (size_t)bz * sA + (size_t)i0 * lda;
  const u16* Bb = B + (size_t)(bz & 7) * sB + (size_t)(bz >> 3) * sB2 + (size_t)j0 * ldb;
  const int tid = threadIdx.x;
  const int lane = tid & 63;
  const int wave = tid >> 6;
  const int wr = wave / WN, wc = wave % WN;
  const int fr = lane & 15;
  const int kg = lane >> 4;
  const int arow = tid >> 2;
  const int aq = tid & 3;

  if constexpr (GMODE == 2) {
    // per-row 1/rowsum from 16 partials (scale arg = pRS), rows are tokens
    if (bz < 8 && tid < BM) {
      const float* pr = scale + ((size_t)bz * NT + i0 + tid) * 16;
      float s = 0.f;
#pragma unroll
      for (int k = 0; k < 16; k++) s += pr[k];
      rsv_l[tid] = 1.0f / s;
    }
  }

  f32x4 acc[FM][FN] = {};

  for (int k0 = 0; k0 < K; k0 += BK) {
#pragma unroll
    for (int c = 0; c < (BM * BK * 2) / 4096; c++)
      g2l16(Ab + (size_t)(arow + c * 64) * lda + k0 + aq * 8,
            (char*)As + c * 4096 + tid * 16);
    if constexpr (BMODE == 0) {
#pragma unroll
      for (int c = 0; c < (BN * BK * 2) / 4096; c++)
        g2l16(Bb + (size_t)(arow + c * 64) * ldb + k0 + aq * 8,
              (char*)Bs + c * 4096 + tid * 16);
    } else {
      // reg-staged B with fused BN apply + relu (BN=64: one 4KB chunk)
      static_assert(BN == 64 || BMODE == 0, "BMODE=1 requires BN=64");
      short8 v = *(const short8*)(Bb + (size_t)arow * ldb + k0 + aq * 8);
      const float* scp = bnsc + (size_t)bz * 512 + k0 + aq * 8;
      const float* shp = bnsh + (size_t)bz * 512 + k0 + aq * 8;
      short8 o;
#pragma unroll
      for (int e = 0; e < 8; e++) {
        float f = fmaxf(fmaf(bf2f((u16)v[e]), scp[e], shp[e]), 0.f);
        o[e] = (short)f2bf(f);
      }
      *(short8*)((char*)Bs + tid * 16) = o;
    }
    __syncthreads();
    short8 fa[FM], fb[FN];
#pragma unroll
    for (int i = 0; i < FM; i++)
      fa[i] = *(const short8*)&As[(wr * FM * 16 + i * 16 + fr) * BK + kg * 8];
#pragma unroll
    for (int j = 0; j < FN; j++)
      fb[j] = *(const short8*)&Bs[(wc * FN * 16 + j * 16 + fr) * BK + kg * 8];
#pragma unroll
    for (int i = 0; i < FM; i++)
#pragma unroll
      for (int j = 0; j < FN; j++)
        acc[i][j] = __builtin_amdgcn_mfma_f32_16x16x32_bf16(fa[i], fb[j], acc[i][j], 0, 0, 0);
    __syncthreads();
  }

  const float scl = (GMODE == 0 && scale) ? scale[bz] : 1.0f;
  const float* brow = bias_row ? bias_row + (size_t)bz * brs : nullptr;
  float* Cf = (float*)C + (size_t)bz * sC;
  u16* Ch = (u16*)C + (size_t)bz * sC;
  float cs[FN] = {}, cs2[FN] = {};         // SMODE 1: per-col partials
  float rs[FM * 4] = {}, rs2[FM * 4] = {}; // SMODE 2: per-row partials
#pragma unroll
  for (int i = 0; i < FM; i++) {
#pragma unroll
    for (int j = 0; j < FN; j++) {
      int col = j0 + wc * FN * 16 + j * 16 + fr;
#pragma unroll
      for (int r = 0; r < 4; r++) {
        int row = i0 + wr * FM * 16 + i * 16 + kg * 4 + r;
        float rb = brow ? brow[row] : 0.0f;
        float sc2 = scl;
        if constexpr (GMODE == 1) sc2 = scale[((row >> 13) << 3) + ((row >> 10) & 7)];
        if constexpr (GMODE == 2) sc2 = (bz < 8) ? rsv_l[row - i0] : 1.0f;
        float v = (acc[i][j][r] + rb) * sc2;
        if constexpr (SMODE == 1) { cs[j] += v; cs2[j] += v * v; }
        if constexpr (SMODE == 2) { rs[i * 4 + r] += v; rs2[i * 4 + r] += v * v; }
        if (storef32) Cf[(size_t)row * ldc + col] = v;
        else Ch[(size_t)row * ldc + col] = f2bf(v);
      }
    }
  }

  if constexpr (SMODE == 1) {
    __shared__ float sred[2][4][FN][16];
#pragma unroll
    for (int j = 0; j < FN; j++) {
      float s = cs[j], s2 = cs2[j];
      s += __shfl_xor(s, 16, 64); s += __shfl_xor(s, 32, 64);
      s2 += __shfl_xor(s2, 16, 64); s2 += __shfl_xor(s2, 32, 64);
      if (lane < 16) { sred[0][wr][j][lane] = s; sred[1][wr][j][lane] = s2; }
    }
    __syncthreads();
    if (tid < FN * 16) {
      int j = tid >> 4, f = tid & 15;
      float s = sred[0][0][j][f] + sred[0][1][j][f] + sred[0][2][j][f] + sred[0][3][j][f];
      float s2 = sred[1][0][j][f] + sred[1][1][j][f] + sred[1][2][j][f] + sred[1][3][j][f];
      int col = j0 + j * 16 + f;
      int chain = by >> 6, ib = by & 63;
      pS[((size_t)chain * 512 + col) * 64 + ib] = s;
      pS2[((size_t)chain * 512 + col) * 64 + ib] = s2;
    }
  }
  if constexpr (SMODE == 2) {
#pragma unroll
    for (int i = 0; i < FM; i++)
#pragma unroll
      for (int r = 0; r < 4; r++) {
        float s = rs[i * 4 + r], s2 = rs2[i * 4 + r];
        s += __shfl_xor(s, 1, 64); s += __shfl_xor(s, 2, 64);
        s += __shfl_xor(s, 4, 64); s += __shfl_xor(s, 8, 64);
        s2 += __shfl_xor(s2, 1, 64); s2 += __shfl_xor(s2, 2, 64);
        s2 += __shfl_xor(s2, 4, 64); s2 += __shfl_xor(s2, 8, 64);
        if (fr == 0) {
          int row = i0 + wr * FM * 16 + i * 16 + kg * 4 + r;
          pS[((size_t)bz * 512 + row) * 128 + bx] = s;
          pS2[((size_t)bz * 512 + row) * 128 + bx] = s2;
        }
      }
  }
}

// ---------------- split-bf16 GEMM (~fp32 accuracy): Out = A*B^T, A,B = hi+lo ----------------
// EMODE 0: store split bf16 pair (Ch,Cl) or fp32 Cf.
// EMODE 1: P = exp(out-20) -> bf16 Ch, plus per-row sum partials pRS[(bz*NT+row)*16+bx].
// Appended hidden-mean cargo (blocks >= nReal).
template <int EMODE>
__global__ __launch_bounds__(256) void gemm_split(
    const u16* __restrict__ Ah_, const u16* __restrict__ Al_, long long sA, int lda,
    const u16* __restrict__ Bh_, const u16* __restrict__ Bl_, long long sB, int ldb,
    float* __restrict__ Cf, u16* __restrict__ Ch, u16* __restrict__ Cl,
    long long sC, int ldc, int K, const float* __restrict__ bias_col, int bcs,
    float* __restrict__ pRS,
    int xbits, int ybits, int nReal,
    int meanBase, const float* __restrict__ xh, const float* __restrict__ yh,
    float* __restrict__ lm) {
  constexpr int BM = 128, BN = 64, BK = 32;
  constexpr int FM = 2, FN = 4;
  __shared__ u16 Ahs[BM * BK];
  __shared__ u16 Als[BM * BK];
  __shared__ u16 Bhs[BN * BK];
  __shared__ u16 Bls[BN * BK];
  int bx, by, bz;
  {
    int id = blockIdx.x;
    if (id >= nReal) { hidden_mean_block(meanBase + (id - nReal), xh, yh, lm); return; }
    bx = id & ((1 << xbits) - 1);
    by = (id >> xbits) & ((1 << ybits) - 1);
    bz = id >> (xbits + ybits);
  }
  const int i0 = by * BM;
  const int j0 = bx * BN;
  const u16* Abh = Ah_ + (size_t)bz * sA + (size_t)i0 * lda;
  const u16* Abl = Al_ + (size_t)bz * sA + (size_t)i0 * lda;
  const u16* Bbh = Bh_ + (size_t)bz * sB + (size_t)j0 * ldb;
  const u16* Bbl = Bl_ + (size_t)bz * sB + (size_t)j0 * ldb;
  const int tid = threadIdx.x;
  const int lane = tid & 63;
  const int wr = tid >> 6;
  const int fr = lane & 15;
  const int kg = lane >> 4;
  const int arow = tid >> 2;
  const int aq = tid & 3;

  f32x4 acc[FM][FN] = {};

  for (int k0 = 0; k0 < K; k0 += BK) {
#pragma unroll
    for (int c = 0; c < 2; c++) {
      g2l16(Abh + (size_t)(arow + c * 64) * lda + k0 + aq * 8,
            (char*)Ahs + c * 4096 + tid * 16);
      g2l16(Abl + (size_t)(arow + c * 64) * lda + k0 + aq * 8,
            (char*)Als + c * 4096 + tid * 16);
    }
    g2l16(Bbh + (size_t)arow * ldb + k0 + aq * 8, (char*)Bhs + tid * 16);
    g2l16(Bbl + (size_t)arow * ldb + k0 + aq * 8, (char*)Bls + tid * 16);
    __syncthreads();
    short8 fah[FM], fal[FM], fbh[FN], fbl[FN];
#pragma unroll
    for (int i = 0; i < FM; i++) {
      fah[i] = *(const short8*)&Ahs[(wr * 32 + i * 16 + fr) * BK + kg * 8];
      fal[i] = *(const short8*)&Als[(wr * 32 + i * 16 + fr) * BK + kg * 8];
    }
#pragma unroll
    for (int j = 0; j < FN; j++) {
      fbh[j] = *(const short8*)&Bhs[(j * 16 + fr) * BK + kg * 8];
      fbl[j] = *(const short8*)&Bls[(j * 16 + fr) * BK + kg * 8];
    }
#pragma unroll
    for (int i = 0; i < FM; i++)
#pragma unroll
      for (int j = 0; j < FN; j++) {
        acc[i][j] = __builtin_amdgcn_mfma_f32_16x16x32_bf16(fah[i], fbh[j], acc[i][j], 0, 0, 0);
        acc[i][j] = __builtin_amdgcn_mfma_f32_16x16x32_bf16(fah[i], fbl[j], acc[i][j], 0, 0, 0);
        acc[i][j] = __builtin_amdgcn_mfma_f32_16x16x32_bf16(fal[i], fbh[j], acc[i][j], 0, 0, 0);
      }
    __syncthreads();
  }

  if constexpr (EMODE == 1) {
    // unnormalized-exp scores: P = exp(S - 20) bf16 + per-row sum partials
    u16* Chb = Ch + (size_t)bz * sC;
    float rsum[FM * 4] = {};
#pragma unroll
    for (int i = 0; i < FM; i++) {
#pragma unroll
      for (int j = 0; j < FN; j++) {
        int col = j0 + j * 16 + fr;
#pragma unroll
        for (int r = 0; r < 4; r++) {
          int row = i0 + wr * 32 + i * 16 + kg * 4 + r;
          float p = __expf(acc[i][j][r] - 20.0f);
          u16 h = f2bf(p);
          Chb[(size_t)row * ldc + col] = h;
          rsum[i * 4 + r] += bf2f(h);
        }
      }
    }
#pragma unroll
    for (int i = 0; i < FM; i++)
#pragma unroll
      for (int r = 0; r < 4; r++) {
        float s = rsum[i * 4 + r];
        s += __shfl_xor(s, 1, 64); s += __shfl_xor(s, 2, 64);
        s += __shfl_xor(s, 4, 64); s += __shfl_xor(s, 8, 64);
        if (fr == 0) {
          int row = i0 + wr * 32 + i * 16 + kg * 4 + r;
          pRS[((size_t)bz * NT + row) * 16 + bx] = s;
        }
      }
  } else {
    const float* bcol = bias_col ? bias_col + (size_t)bz * bcs : nullptr;
    float* Cfb = Cf ? Cf + (size_t)bz * sC : nullptr;
    u16* Chb = Ch ? Ch + (size_t)bz * sC : nullptr;
    u16* Clb = Cl ? Cl + (size_t)bz * sC : nullptr;
#pragma unroll
    for (int i = 0; i < FM; i++) {
#pragma unroll
      for (int j = 0; j < FN; j++) {
        int col = j0 + j * 16 + fr;
        float cb = bcol ? bcol[col] : 0.0f;
#pragma unroll
        for (int r = 0; r < 4; r++) {
          int row = i0 + wr * 32 + i * 16 + kg * 4 + r;
          float v = acc[i][j][r] + cb;
          if (Cfb) {
            Cfb[(size_t)row * ldc + col] = v;
          } else {
            u16 h = f2bf(v);
            Chb[(size_t)row * ldc + col] = h;
            Clb[(size_t)row * ldc + col] = f2bf(v - bf2f(h));
          }
        }
      }
    }
  }
}

// ---------------- BN stats reduce: NP partials -> scale/shift ----------------
template <int NP>
__global__ __launch_bounds__(128) void bnstats_reduce_np(
    const float* __restrict__ pS, const float* __restrict__ pS2,
    const float* __restrict__ g, const float* __restrict__ bet,
    float* __restrict__ scale, float* __restrict__ shift) {
  int cg = blockIdx.x;  // [chain][c]
  int c = cg & 511;
  int t = threadIdx.x;
  float s = 0.f, s2 = 0.f;
  if (t < NP) { s = pS[(size_t)cg * NP + t]; s2 = pS2[(size_t)cg * NP + t]; }
  s = waveSum(s); s2 = waveSum(s2);
  __shared__ float sb[4];
  int lane = t & 63, wid = t >> 6;
  if (lane == 0) { sb[wid] = s; sb[wid + 2] = s2; }
  __syncthreads();
  if (t == 0) {
    float S = sb[0] + sb[1];
    float S2 = sb[2] + sb[3];
    const float invn = 1.0f / (BB * NT);
    float mean = S * invn;
    float var = S2 * invn - mean * mean;
    float inv = rsqrtf(var + BN_EPS);
    float sc = g[c] * inv;
    scale[cg] = sc;
    shift[cg] = bet[c] - mean * sc;
  }
}

// ---------------- BN final: z2 [2][512][8192] + x/y fp32 -> out ----------------
// Stats reduced in-block from channel-major partials (NP=128, one channel per block).
__global__ __launch_bounds__(256) void bn_final_kernel(
    const u16* __restrict__ Z2, const float* __restrict__ X, const float* __restrict__ Y,
    const float* __restrict__ pS, const float* __restrict__ pS2,
    const float* __restrict__ g, const float* __restrict__ bet,
    float* __restrict__ Out) {
  size_t e0 = (size_t)blockIdx.x * 256;
  int chain = (int)(e0 >> 20);
  int c = (int)((e0 & 1048575) >> 11);  // constant within block (256 groups < 2048/channel)
  int cg = chain * 512 + c;
  int t = threadIdx.x;
  float s = 0.f, s2 = 0.f;
  if (t < 128) { s = pS[(size_t)cg * 128 + t]; s2 = pS2[(size_t)cg * 128 + t]; }
  s = waveSum(s); s2 = waveSum(s2);
  __shared__ float sb[8];
  int lane = t & 63, wid = t >> 6;
  if (lane == 0) { sb[wid] = s; sb[wid + 4] = s2; }
  __syncthreads();
  __shared__ float ssc, ssh;
  if (t == 0) {
    float S = sb[0] + sb[1] + sb[2] + sb[3];
    float S2 = sb[4] + sb[5] + sb[6] + sb[7];
    const float invn = 1.0f / (BB * NT);
    float mean = S * invn;
    float var = S2 * invn - mean * mean;
    float inv = rsqrtf(var + BN_EPS);
    float sc = g[c] * inv;
    ssc = sc;
    ssh = bet[c] - mean * sc;
  }
  __syncthreads();
  size_t e = e0 + t;
  size_t ec = e & 1048575;
  int r = (int)(ec & 2047);
  int b = r >> 8;
  uint2 u = ((const uint2*)Z2)[e];
  float a0 = bf2f((u16)u.x), a1 = bf2f((u16)(u.x >> 16));
  float a2 = bf2f((u16)u.y), a3 = bf2f((u16)(u.y >> 16));
  float sc = ssc, sh = ssh;
  size_t xi = ((size_t)b * CC + c) * 256 + (r & 255);
  const float* Xs = chain ? Y : X;
  float4 xv = ((const float4*)Xs)[xi];
  float4 o;
  o.x = fmaxf(fmaf(a0, sc, sh) + xv.x, 0.f);
  o.y = fmaxf(fmaf(a1, sc, sh) + xv.y, 0.f);
  o.z = fmaxf(fmaf(a2, sc, sh) + xv.z, 0.f);
  o.w = fmaxf(fmaf(a3, sc, sh) + xv.w, 0.f);
  ((float4*)(Out + (size_t)chain * 4194304))[xi] = o;
}

extern "C" void kernel_launch(void* const* d_in, const int* in_sizes, int n_in,
                              void* d_out, int out_size, void* d_ws, size_t ws_size,
                              hipStream_t stream) {
  (void)in_sizes; (void)n_in; (void)out_size; (void)ws_size;
  const float* x    = (const float*)d_in[0];
  const float* y    = (const float*)d_in[1];
  const float* xh   = (const float*)d_in[2];
  const float* yh   = (const float*)d_in[3];
  const float* qW   = (const float*)d_in[4];
  const float* qb   = (const float*)d_in[5];
  const float* kW   = (const float*)d_in[6];
  const float* kb   = (const float*)d_in[7];
  const float* v1W  = (const float*)d_in[8];
  const float* v1b  = (const float*)d_in[9];
  const float* v2W  = (const float*)d_in[10];
  const float* v2b  = (const float*)d_in[11];
  const float* hw1  = (const float*)d_in[12];
  const float* hw2  = (const float*)d_in[13];
  const float* g1W1 = (const float*)d_in[14];
  const float* g1b1 = (const float*)d_in[15];
  const float* g1W2 = (const float*)d_in[16];
  const float* g1b2 = (const float*)d_in[17];
  const float* g2W1 = (const float*)d_in[18];
  const float* g2b1 = (const float*)d_in[19];
  const float* g2W2 = (const float*)d_in[20];
  const float* g2b2 = (const float*)d_in[21];
  const float* rW1  = (const float*)d_in[22];
  // d_in[23] = rb1 dropped (BN absorbs constant bias)
  const float* bn1g = (const float*)d_in[24];
  const float* bn1b = (const float*)d_in[25];
  const float* rW2  = (const float*)d_in[26];
  // d_in[27] = rb2 dropped
  const float* bn2g = (const float*)d_in[28];
  const float* bn2b = (const float*)d_in[29];
  float* out = (float*)d_out;

  // ---- workspace layout ----
  float* ws  = (float*)d_ws;
  float* lm  = ws;                  // 81,920
  float* gam = ws + 81920;          // 16
  float* scA = ws + 81936;          // 1,024 (2 chains)
  float* shA = ws + 82960;          // 1,024
  float* qkb = ws + 83984;          // 128
  float* vb  = ws + 84112;          // 1,024
  float* pS  = ws + 85136;          // 262,144 (max 2*512*128)
  float* pS2 = ws + 347280;         // 262,144
  float* pRS = ws + 609424;         // 131,072 rowsum partials (8192x16)
  u16* U     = (u16*)(ws + 8998032);
  u16* Wqh = U;                     // 32,768 | order: Wqh,Wql,Wkh,Wkl
  u16* Wql = U + 32768;
  u16* Wkh = U + 65536;
  u16* Wkl = U + 98304;
  u16* Wv1 = U + 131072;            // 262,144 each, Wv1->Wv2 contiguous
  u16* Wv2 = U + 393216;
  u16* Wr1 = U + 655360;
  u16* Wr2 = U + 917504;
  u16* xth = U + 1179648;           // 4,194,304 each; xth->yth contiguous
  u16* yth = xth + 4194304;
  u16* xtl = yth + 4194304;
  u16* ytl = xtl + 4194304;
  u16* q_h = ytl + 4194304;         // 524,288 each; q->k stride 1,048,576
  u16* q_l = q_h + 524288;
  u16* k_h = q_l + 524288;
  u16* k_l = k_h + 524288;
  u16* v1  = k_l + 524288;          // 4,194,304 each; v1->v2 contiguous
  u16* v2  = v1 + 4194304;
  u16* attn  = v2 + 4194304;        // 8,388,608 (unnormalized P)
  u16* attnT = attn + 8388608;      // 8,388,608 (normalized, contiguous after attn)
  // overlays (stream-serialized lifetimes):
  u16* o1t = xth;   // [2][8192][512] token-major outs (pre-gamma)
  u16* z0  = v1;    // [2][8192][512] conv1 out (M=16384 merged, gamma applied)
  u16* z2  = attn;  // [2][512][8192] conv2 out (cm)

  // 1) pre-work: weight converts + x/y transpose (hidden means ride in GEMMs below)
  PreArgs pa;
  pa.v1W = v1W; pa.v2W = v2W; pa.rW1 = rW1; pa.rW2 = rW2; pa.Wdst = Wv1;
  pa.qW = qW; pa.kW = kW; pa.qh = Wqh; pa.ql = Wql; pa.kh = Wkh; pa.kl = Wkl;
  pa.qb = qb; pa.kb = kb; pa.v1b = v1b; pa.v2b = v2b; pa.qkb = qkb; pa.vb = vb;
  pa.x = x; pa.y = y; pa.xth = xth; pa.xtl = xtl; pa.yth = yth; pa.ytl = ytl;
  pre_kernel<<<3136, 256, 0, stream>>>(pa);

  // 2) v-projections (BN=128, 512 real) + 5120 mean blocks (appended tail)
  gemm_bf16<128, 0, 0, 0><<<512 + 5120, 256, 0, stream>>>(
      Wv1, 262144, CC, xth, 4194304, 0, CC, v1, 4194304, BB * NT, CC, 0, vb, 512,
      nullptr, nullptr, nullptr, nullptr, nullptr, 6, 2, 512, 0, xh, yh, lm);
  // q/k projections (128 real) + 3072 mean blocks
  gemm_split<0><<<128 + 3072, 256, 0, stream>>>(
      xth, xtl, 4194304, CC, Wqh, Wql, 65536, CC,
      nullptr, q_h, q_l, 1048576, DQK, CC, qkb, 64, nullptr,
      0, 6, 128, 5120, xh, yh, lm);

  // 3) scores -> P = exp(S-20) bf16 + rowsum partials (1024 real) + 4096 mean blocks
  gemm_split<1><<<1024 + 4096, 256, 0, stream>>>(
      q_h, q_l, (long long)NT * DQK, DQK, k_h, k_l, (long long)NT * DQK, DQK,
      nullptr, attn, nullptr, (long long)NT * NT, NT, DQK, nullptr, 0, pRS,
      4, 3, 1024, 8192, xh, yh, lm);
  transpose_attn_kernel<<<dim3(16, 16, 8), 256, 0, stream>>>(attn, attnT, pRS);

  // 4) attention-apply (BN=128, 512 real; out1 row-normalized from pRS) + 8192 mean
  gemm_bf16<128, 0, 2, 0><<<512 + 8192, 256, 0, stream>>>(
      attn, (long long)NT * NT, NT, v1, NT, 4194304, BB * NT,
      o1t, (long long)NT * CC, CC, NT, 0, nullptr, 0, pRS, nullptr, nullptr,
      nullptr, nullptr, 2, 3, 512, 12288, xh, yh, lm);

  // 5) gamma (lm complete), then residual chains
  gamma_kernel<<<16, 256, 0, stream>>>(lm, hw1, hw2, g1W1, g1b1, g1W2, g1b2,
                                       g2W1, g2b1, g2W2, g2b2, gam);
  // conv1: per-row gamma + fused token-major stats (M=16384 merged)
  gemm_bf16<64, 1, 1, 0><<<dim3(8, 128, 1), 256, 0, stream>>>(
      o1t, 0, CC, Wr1, 0, 0, CC, z0, 0, CC, CC, 0, nullptr, 0, gam, pS, pS2,
      nullptr, nullptr, 0, 0, 0, 0, nullptr, nullptr, nullptr);
  bnstats_reduce_np<64><<<1024, 128, 0, stream>>>(pS, pS2, bn1g, bn1b, scA, shA);
  // conv2: B = bn_apply(z0) fused into reg-staging; channel-major stats fused
  gemm_bf16<64, 2, 0, 1><<<dim3(128, 4, 2), 256, 0, stream>>>(
      Wr2, 0, CC, z0, 4194304, 0, CC, z2, 4194304, BB * NT, CC, 0, nullptr, 0, nullptr,
      pS, pS2, scA, shA, 0, 0, 0, 0, nullptr, nullptr, nullptr);
  // bn_final: stats reduced in-block from NP=128 partials
  bn_final_kernel<<<8192, 256, 0, stream>>>(z2, x, y, pS, pS2, bn2g, bn2b, out);
}